// Round 1
// baseline (442.027 us; speedup 1.0000x reference)
//
#include <hip/hip_runtime.h>
#include <hip/hip_bf16.h>

#define B_   8
#define H_   128
#define W_   128
#define C_   64
#define F_   128
#define KDIM 5184     // 9 taps * 576
#define BHW_ 131072   // B_*H_*W_

// fused-tile geometry
#define TH   8
#define TW   16
#define HY   10       // TH+2
#define HX   18       // TW+2
#define NPX  180      // HY*HX

// LDS layout (units: shorts)
#define STILE 0       // 180*64            = 11520 shorts (sampled tap-t tile, swizzled)
#define BTILE 11520   // 3 chunks *128*64  = 24576 shorts (W slices, swizzled)
#define PARMW 36096   // 180 float4        =  1440 shorts (bilinear weights)
#define PARMO 37536   // 180 int4          =  1440 shorts (corner offsets + px)
#define LDSSZ 38976   // 77952 B -> 2 blocks/CU

typedef __bf16 bf16x8 __attribute__((ext_vector_type(8)));
typedef float  f32x4  __attribute__((ext_vector_type(4)));

__device__ __forceinline__ unsigned short f2bf(float f) {
  unsigned int u = __float_as_uint(f);
  unsigned int r = (u + 0x7fffu + ((u >> 16) & 1u)) >> 16;
  return (unsigned short)r;
}

// ---------------- offset conv -> PLANAR offsets: offsP[o][b,h,w]
// 2 adjacent pixels per thread: each LDS weight float now feeds 2 FMAs,
// halving LDS traffic and wave count vs the 1-px version.
__global__ __launch_bounds__(256) void offs_conv_kernel(
    const float* __restrict__ x, const float* __restrict__ Woff,
    const float* __restrict__ boff, float* __restrict__ offsP) {
  __shared__ float Wl[9 * 18 * 64];   // [tap][o][c]
  const int tid = threadIdx.x;
  for (int i = tid; i < 9 * 64 * 18; i += 256) {
    int tap = i / 1152;
    int r   = i % 1152;
    int c   = r / 18;
    int o   = r % 18;
    Wl[(tap * 18 + o) * 64 + c] = Woff[i];
  }
  __syncthreads();
  const int q  = tid & 3;           // channel quarter
  const int c0 = q * 16;
  const int pl = tid >> 2;          // 0..63
  const int p0 = blockIdx.x * 128 + 2 * pl;   // even pixel; p1 = p0+1 same row
  const int w0 = p0 & 127;          // 0..126
  const int h  = (p0 >> 7) & 127;   // block-uniform
  const int b  = p0 >> 14;          // block-uniform

  float acc[18][2] = {};

  for (int ky = 0; ky < 3; ++ky) {
    int hy = h + ky - 1;
    if (hy < 0 || hy >= H_) continue;          // scalar branch (h uniform)
    const float* rowp = x + ((size_t)(b * H_ + hy) * W_) * C_ + c0;
    for (int kx = 0; kx < 3; ++kx) {
      int wx0 = w0 + kx - 1;                   // -1..127
      int wx1 = wx0 + 1;                       //  0..128
      float4 a0 = {}, a1 = {}, a2 = {}, a3 = {};
      float4 e0 = {}, e1 = {}, e2 = {}, e3 = {};
      if ((unsigned)wx0 < (unsigned)W_) {      // zero-pad: OOB contributes +0
        const float* p = rowp + wx0 * C_;
        a0 = ((const float4*)p)[0]; a1 = ((const float4*)p)[1];
        a2 = ((const float4*)p)[2]; a3 = ((const float4*)p)[3];
      }
      if ((unsigned)wx1 < (unsigned)W_) {
        const float* p = rowp + wx1 * C_;
        e0 = ((const float4*)p)[0]; e1 = ((const float4*)p)[1];
        e2 = ((const float4*)p)[2]; e3 = ((const float4*)p)[3];
      }
      const float* wl = &Wl[(ky * 3 + kx) * 18 * 64 + c0];
#pragma unroll
      for (int o = 0; o < 18; ++o) {
        const float4* wvp = (const float4*)(wl + o * 64);
        float4 w0v = wvp[0], w1v = wvp[1], w2v = wvp[2], w3v = wvp[3];
        acc[o][0] += a0.x * w0v.x + a0.y * w0v.y + a0.z * w0v.z + a0.w * w0v.w
                   + a1.x * w1v.x + a1.y * w1v.y + a1.z * w1v.z + a1.w * w1v.w
                   + a2.x * w2v.x + a2.y * w2v.y + a2.z * w2v.z + a2.w * w2v.w
                   + a3.x * w3v.x + a3.y * w3v.y + a3.z * w3v.z + a3.w * w3v.w;
        acc[o][1] += e0.x * w0v.x + e0.y * w0v.y + e0.z * w0v.z + e0.w * w0v.w
                   + e1.x * w1v.x + e1.y * w1v.y + e1.z * w1v.z + e1.w * w1v.w
                   + e2.x * w2v.x + e2.y * w2v.y + e2.z * w2v.z + e2.w * w2v.w
                   + e3.x * w3v.x + e3.y * w3v.y + e3.z * w3v.z + e3.w * w3v.w;
      }
    }
  }
#pragma unroll
  for (int o = 0; o < 18; ++o) {
#pragma unroll
    for (int j = 0; j < 2; ++j) {
      acc[o][j] += __shfl_xor(acc[o][j], 1);
      acc[o][j] += __shfl_xor(acc[o][j], 2);
    }
  }
  for (int o = q; o < 18; o += 4) {
    float bo = boff[o];
    float2 v = make_float2(acc[o][0] + bo, acc[o][1] + bo);
    *(float2*)&offsP[(size_t)o * BHW_ + p0] = v;   // p0 even -> 8B aligned
  }
}

// ---------------- W (5184,128) fp32 -> Wt (128,5184) bf16, LDS-tiled transpose
__global__ __launch_bounds__(256) void wt_prep_kernel(
    const float* __restrict__ Wf, unsigned short* __restrict__ Wt) {
  __shared__ float Wl[64][65];
  const int tid = threadIdx.x;
  const int kk0 = (blockIdx.x % 81) * 64;
  const int f0  = (blockIdx.x / 81) * 64;
  for (int i = tid; i < 4096; i += 256) {
    int kk = i >> 6, f = i & 63;
    Wl[kk][f] = Wf[(size_t)(kk0 + kk) * F_ + f0 + f];
  }
  __syncthreads();
  for (int i = tid; i < 4096; i += 256) {
    int f = i >> 6, kk = i & 63;
    Wt[(size_t)(f0 + f) * KDIM + kk0 + kk] = f2bf(Wl[kk][f]);
  }
}

// ---------------- fused bilinear-sample + implicit-im2col MFMA conv
// grid = 1024 blocks (XCD-banded: one image per XCD), block = 256 (4 waves).
__global__ __launch_bounds__(256, 2) void fused_kernel(
    const float* __restrict__ x, const float* __restrict__ offsP,
    const unsigned short* __restrict__ Wt, const float* __restrict__ bias,
    float* __restrict__ out) {
  __shared__ __align__(16) short lds[LDSSZ];
  const int tid  = threadIdx.x;
  const int lane = tid & 63;
  const int wv   = tid >> 6;
  // XCD-banded decode: blocks (bid&7) own image (bid&7)
  const int gr   = (blockIdx.x & 7) * 128 + (blockIdx.x >> 3);
  const int b    = gr >> 7;
  const int tile = gr & 127;
  const int ty   = tile >> 3, tx = tile & 7;
  const int gy0  = ty * TH, gx0 = tx * TW;
  const float* xb = x + (size_t)b * (H_ * W_ * C_);

  const int l15  = lane & 15, quad = lane >> 4;
  const int sub  = lane & 7,  rig  = lane >> 3;
  const int wm   = (wv >> 1) * 64, wn = (wv & 1) * 64;

  f32x4 acc[4][4] = {};

  // A-frag pixel-index base per m-frag i: my = (wv>>1)*4 + i, p0 = my*HX + l15
  int p0[4];
#pragma unroll
  for (int i = 0; i < 4; ++i) p0[i] = ((wv >> 1) * 4 + i) * HX + l15;
  // B-frag LDS offsets (chunk 0): row n = wn+16j+l15, swizzle (ks*4+quad)^(l15&7)
  int bo[2][4];
#pragma unroll
  for (int ks = 0; ks < 2; ++ks)
#pragma unroll
    for (int j = 0; j < 4; ++j)
      bo[ks][j] = BTILE + (wn + 16 * j + l15) * 64 + (((ks * 4 + quad) ^ (l15 & 7)) * 8);

  const int s_py = tid / HX, s_px = tid - s_py * HX;   // S1 task coords (tid<180)

  for (int t = 0; t < 9; ++t) {
    __syncthreads();   // all waves done reading stile/params of t-1
    // ---- S1: per-halo-pixel bilinear params
    if (tid < NPX) {
      int gy = gy0 + s_py - 1, gx = gx0 + s_px - 1;
      float wa = 0.f, wb = 0.f, wc = 0.f, wd = 0.f;
      int oA = 0, oB = 0, oC = 0, oD = 0;
      if ((unsigned)gy < (unsigned)H_ && (unsigned)gx < (unsigned)W_) {
        int pix = (b * H_ + gy) * W_ + gx;
        float offx = offsP[(size_t)(2 * t) * BHW_ + pix];
        float offy = offsP[(size_t)(2 * t + 1) * BHW_ + pix];
        float lx = (float)gx + (float)(t % 3 - 1) + offx;
        float ly = (float)gy + (float)(t / 3 - 1) + offy;
        lx = fminf(fmaxf(lx, 0.f), 127.f);
        ly = fminf(fmaxf(ly, 0.f), 127.f);
        float fx = floorf(lx), fy = floorf(ly);
        float x0c = fminf(fmaxf(fx, 0.f), 127.f);
        float x1c = fminf(fmaxf(fx + 1.f, 0.f), 127.f);
        float y0c = fminf(fmaxf(fy, 0.f), 127.f);
        float y1c = fminf(fmaxf(fy + 1.f, 0.f), 127.f);
        wa = (x1c - lx) * (y1c - ly);
        wb = (x1c - lx) * (ly - y0c);
        wc = (lx - x0c) * (y1c - ly);
        wd = (lx - x0c) * (ly - y0c);
        int ix0 = (int)x0c, ix1 = (int)x1c, iy0 = (int)y0c, iy1 = (int)y1c;
        oA = (iy0 * W_ + ix0) * C_;
        oB = (iy1 * W_ + ix0) * C_;
        oC = (iy0 * W_ + ix1) * C_;
        oD = (iy1 * W_ + ix1) * C_;
      }
      ((float4*)&lds[PARMW])[tid] = make_float4(wa, wb, wc, wd);
      ((int4*)&lds[PARMO])[tid]  = make_int4(oA | (s_px << 20), oB, oC, oD);
    }
    __syncthreads();   // params visible
    // ---- S2: gather + blend + bf16 pack into stile (1440 tasks)
#pragma unroll
    for (int it = 0; it < 6; ++it) {
      int u = it * 256 + tid;
      if (u < NPX * 8) {
        int p = u >> 3, j = u & 7;
        float4 wv4 = ((const float4*)&lds[PARMW])[p];
        int4   ov4 = ((const int4*)&lds[PARMO])[p];
        int pxl = ov4.x >> 20;
        const float* pa = xb + (ov4.x & 0xFFFFF) + j * 8;
        const float* pb = xb + ov4.y + j * 8;
        const float* pc = xb + ov4.z + j * 8;
        const float* pd = xb + ov4.w + j * 8;
        float4 A0 = ((const float4*)pa)[0], A1 = ((const float4*)pa)[1];
        float4 B0 = ((const float4*)pb)[0], B1 = ((const float4*)pb)[1];
        float4 C0 = ((const float4*)pc)[0], C1 = ((const float4*)pc)[1];
        float4 D0 = ((const float4*)pd)[0], D1 = ((const float4*)pd)[1];
        union { unsigned short s[8]; uint4 v; } uu;
        uu.s[0] = f2bf(wv4.x * A0.x + wv4.y * B0.x + wv4.z * C0.x + wv4.w * D0.x);
        uu.s[1] = f2bf(wv4.x * A0.y + wv4.y * B0.y + wv4.z * C0.y + wv4.w * D0.y);
        uu.s[2] = f2bf(wv4.x * A0.z + wv4.y * B0.z + wv4.z * C0.z + wv4.w * D0.z);
        uu.s[3] = f2bf(wv4.x * A0.w + wv4.y * B0.w + wv4.z * C0.w + wv4.w * D0.w);
        uu.s[4] = f2bf(wv4.x * A1.x + wv4.y * B1.x + wv4.z * C1.x + wv4.w * D1.x);
        uu.s[5] = f2bf(wv4.x * A1.y + wv4.y * B1.y + wv4.z * C1.y + wv4.w * D1.y);
        uu.s[6] = f2bf(wv4.x * A1.z + wv4.y * B1.z + wv4.z * C1.z + wv4.w * D1.z);
        uu.s[7] = f2bf(wv4.x * A1.w + wv4.y * B1.w + wv4.z * C1.w + wv4.w * D1.w);
        *(uint4*)&lds[STILE + p * 64 + ((j ^ (pxl & 7)) * 8)] = uu.v;
      }
    }
    // ---- conv: 3 ky2 groups; per group stage 3 kx2 W-chunks (48 KB) then MFMA
    for (int g = 0; g < 3; ++g) {
      __syncthreads();   // btile free (and on g=0: stile writes ordered before reads)
#pragma unroll
      for (int i = 0; i < 12; ++i) {
        int slot = wv * 12 + i;              // 0..47
        int chunk = slot >> 4;               // kx2
        int f = ((slot & 15) * 8) + rig;
        int tap2 = g * 3 + chunk;
        const short* src = (const short*)Wt + (size_t)f * KDIM +
                           tap2 * 576 + t * 64 + ((sub ^ rig) * 8);
        __builtin_amdgcn_global_load_lds(
            (const __attribute__((address_space(1))) void*)src,
            (__attribute__((address_space(3))) void*)&lds[BTILE + slot * 512],
            16, 0, 0);
      }
      __syncthreads();   // staged visible + stile visible
      const int off2 = g * HX;               // ky2 = g
#pragma unroll
      for (int c3 = 0; c3 < 3; ++c3) {       // kx2 = c3
        int t1 = (l15 + c3) & 7;
        int xr0 = ((quad ^ t1) * 8);
        int xr1 = (((4 + quad) ^ t1) * 8);
#pragma unroll
        for (int ks = 0; ks < 2; ++ks) {
          int xr = ks ? xr1 : xr0;
          bf16x8 af[4], bfr[4];
#pragma unroll
          for (int i = 0; i < 4; ++i)
            af[i] = *(const bf16x8*)&lds[(p0[i] + off2 + c3) * 64 + xr];
#pragma unroll
          for (int j = 0; j < 4; ++j)
            bfr[j] = *(const bf16x8*)&lds[bo[ks][j] + c3 * 8192];
#pragma unroll
          for (int i = 0; i < 4; ++i)
#pragma unroll
            for (int j = 0; j < 4; ++j)
              acc[i][j] = __builtin_amdgcn_mfma_f32_16x16x32_bf16(
                  af[i], bfr[j], acc[i][j], 0, 0, 0);
        }
      }
    }
  }

  // ---- epilogue
  float bj[4];
#pragma unroll
  for (int j = 0; j < 4; ++j) bj[j] = bias[wn + 16 * j + l15];
#pragma unroll
  for (int i = 0; i < 4; ++i) {
    int gy = gy0 + (wv >> 1) * 4 + i;
#pragma unroll
    for (int r = 0; r < 4; ++r) {
      int gx = gx0 + quad * 4 + r;
      float* rp = out + ((size_t)((b * H_ + gy) * W_ + gx)) * F_;
#pragma unroll
      for (int j = 0; j < 4; ++j)
        rp[wn + 16 * j + l15] = acc[i][j][r] + bj[j];
    }
  }
}

extern "C" void kernel_launch(void* const* d_in, const int* in_sizes, int n_in,
                              void* d_out, int out_size, void* d_ws, size_t ws_size,
                              hipStream_t stream) {
  (void)in_sizes; (void)n_in; (void)out_size; (void)ws_size;
  const float* x    = (const float*)d_in[0];
  const float* Woff = (const float*)d_in[1];
  const float* boff = (const float*)d_in[2];
  const float* Wf   = (const float*)d_in[3];
  const float* bias = (const float*)d_in[4];
  float* out = (float*)d_out;

  char* ws = (char*)d_ws;
  size_t off_bytes = (size_t)18 * BHW_ * 4;          // 9.44 MB planar offsets
  size_t p1 = (off_bytes + 255) & ~(size_t)255;
  float*          offsP = (float*)ws;
  unsigned short* Wt    = (unsigned short*)(ws + p1); // 1.33 MB

  offs_conv_kernel<<<BHW_ / 128, 256, 0, stream>>>(x, Woff, boff, offsP);
  wt_prep_kernel<<<162, 256, 0, stream>>>(Wf, Wt);
  fused_kernel<<<1024, 256, 0, stream>>>(x, offsP, Wt, bias, out);
}